// Round 5
// baseline (253.912 us; speedup 1.0000x reference)
//
#include <hip/hip_runtime.h>

#define ERROR_OK 0.1f

constexpr int BLOCK  = 256;
constexpr int GRID   = 2048;   // 8192 waves = HW wave capacity
constexpr int UNROLL = 4;      // 8 independent nt 16B loads in flight

typedef float v4f __attribute__((ext_vector_type(4)));

// Stage 1: grid-stride nt-load streaming, unrolled x4.
// R4: nt loads (L1 bypass) broke the 2.6 TB/s L1-MSHR wall -> ~3.4 TB/s.
// Now per-wave MLP (2 outstanding loads at VGPR=12) is the suspected limiter;
// unroll was neutral in R2/R3 only because the MSHR cap was downstream.
__global__ __launch_bounds__(BLOCK, 4) void dz_partial_kernel(
    const v4f* __restrict__ a,
    const v4f* __restrict__ b,
    float* __restrict__ partials,
    int n4)
{
    const int tid    = blockIdx.x * BLOCK + threadIdx.x;
    const int stride = GRID * BLOCK;

    float acc0 = 0.0f, acc1 = 0.0f, acc2 = 0.0f, acc3 = 0.0f;

    int i = tid;
    for (; i + (UNROLL - 1) * stride < n4; i += UNROLL * stride) {
        v4f va[UNROLL], vb[UNROLL];
        #pragma unroll
        for (int k = 0; k < UNROLL; ++k) {
            va[k] = __builtin_nontemporal_load(&a[i + k * stride]);
            vb[k] = __builtin_nontemporal_load(&b[i + k * stride]);
        }
        #pragma unroll
        for (int k = 0; k < UNROLL; ++k) {
            float d0 = va[k][0] - vb[k][0];
            float d1 = va[k][1] - vb[k][1];
            float d2 = va[k][2] - vb[k][2];
            float d3 = va[k][3] - vb[k][3];
            d0 = (fabsf(d0) < ERROR_OK) ? 0.0f : d0;
            d1 = (fabsf(d1) < ERROR_OK) ? 0.0f : d1;
            d2 = (fabsf(d2) < ERROR_OK) ? 0.0f : d2;
            d3 = (fabsf(d3) < ERROR_OK) ? 0.0f : d3;
            acc0 += d0 * d0;
            acc1 += d1 * d1;
            acc2 += d2 * d2;
            acc3 += d3 * d3;
        }
    }
    // tail (not hit for N=2^25: 16 iters/thread = 4 clean unrolled passes)
    for (; i < n4; i += stride) {
        v4f va = __builtin_nontemporal_load(&a[i]);
        v4f vb = __builtin_nontemporal_load(&b[i]);
        float d0 = va[0] - vb[0];
        float d1 = va[1] - vb[1];
        float d2 = va[2] - vb[2];
        float d3 = va[3] - vb[3];
        d0 = (fabsf(d0) < ERROR_OK) ? 0.0f : d0;
        d1 = (fabsf(d1) < ERROR_OK) ? 0.0f : d1;
        d2 = (fabsf(d2) < ERROR_OK) ? 0.0f : d2;
        d3 = (fabsf(d3) < ERROR_OK) ? 0.0f : d3;
        acc0 += d0 * d0;
        acc1 += d1 * d1;
        acc2 += d2 * d2;
        acc3 += d3 * d3;
    }

    float sum = (acc0 + acc1) + (acc2 + acc3);

    // wave-64 butterfly reduce
    #pragma unroll
    for (int off = 32; off > 0; off >>= 1)
        sum += __shfl_down(sum, off, 64);

    __shared__ float smem[BLOCK / 64];
    const int lane = threadIdx.x & 63;
    const int wave = threadIdx.x >> 6;
    if (lane == 0) smem[wave] = sum;
    __syncthreads();

    if (threadIdx.x == 0) {
        float s = 0.0f;
        #pragma unroll
        for (int w = 0; w < BLOCK / 64; ++w) s += smem[w];
        partials[blockIdx.x] = s;
    }
}

// Stage 2: single block reduces GRID partials, scales by 1/N. Deterministic.
__global__ __launch_bounds__(BLOCK) void dz_final_kernel(
    const float* __restrict__ partials,
    float* __restrict__ out,
    int nparts,
    float inv_n)
{
    float sum = 0.0f;
    for (int i = threadIdx.x; i < nparts; i += BLOCK)
        sum += partials[i];

    #pragma unroll
    for (int off = 32; off > 0; off >>= 1)
        sum += __shfl_down(sum, off, 64);

    __shared__ float smem[BLOCK / 64];
    const int lane = threadIdx.x & 63;
    const int wave = threadIdx.x >> 6;
    if (lane == 0) smem[wave] = sum;
    __syncthreads();

    if (threadIdx.x == 0) {
        float s = 0.0f;
        #pragma unroll
        for (int w = 0; w < BLOCK / 64; ++w) s += smem[w];
        out[0] = s * inv_n;
    }
}

extern "C" void kernel_launch(void* const* d_in, const int* in_sizes, int n_in,
                              void* d_out, int out_size, void* d_ws, size_t ws_size,
                              hipStream_t stream) {
    const v4f* a    = (const v4f*)d_in[0];
    const v4f* b    = (const v4f*)d_in[1];
    float* out      = (float*)d_out;
    float* partials = (float*)d_ws;   // GRID floats = 8 KiB scratch

    const int n  = in_sizes[0];       // 33554432, divisible by 4
    const int n4 = n / 4;

    dz_partial_kernel<<<GRID, BLOCK, 0, stream>>>(a, b, partials, n4);
    dz_final_kernel<<<1, BLOCK, 0, stream>>>(partials, out, GRID, 1.0f / (float)n);
}

// Round 6
// 248.663 us; speedup vs baseline: 1.0211x; 1.0211x over previous
//
#include <hip/hip_runtime.h>

#define ERROR_OK 0.1f

constexpr int BLOCK  = 256;
constexpr int GRID   = 2048;
constexpr int UNROLL = 8;     // 16 nt 16B loads issued before first consume

typedef float v4f __attribute__((ext_vector_type(4)));

// Stage 1: BLOCK-CONTIGUOUS spans (vs grid-stride). Each block owns
// n4/GRID consecutive float4s per stream (64 KB) -> DRAM page locality per
// CU now that nt loads bypass L1 and hit TCC/HBM directly. Deep unroll x8:
// all 16 loads issued before first use. launch_bounds(256,4): VGPR cap 128.
__global__ __launch_bounds__(BLOCK, 4) void dz_partial_kernel(
    const v4f* __restrict__ a,
    const v4f* __restrict__ b,
    float* __restrict__ partials,
    int n4)
{
    const int chunk = n4 / GRID;              // float4s per block (4096)
    const int base  = blockIdx.x * chunk + threadIdx.x;
    const int iters = chunk / BLOCK;          // 16

    float acc0 = 0.0f, acc1 = 0.0f, acc2 = 0.0f, acc3 = 0.0f;

    int j = 0;
    for (; j + UNROLL <= iters; j += UNROLL) {
        v4f va[UNROLL], vb[UNROLL];
        #pragma unroll
        for (int k = 0; k < UNROLL; ++k) {
            const int idx = base + (j + k) * BLOCK;
            va[k] = __builtin_nontemporal_load(&a[idx]);
            vb[k] = __builtin_nontemporal_load(&b[idx]);
        }
        #pragma unroll
        for (int k = 0; k < UNROLL; ++k) {
            float d0 = va[k][0] - vb[k][0];
            float d1 = va[k][1] - vb[k][1];
            float d2 = va[k][2] - vb[k][2];
            float d3 = va[k][3] - vb[k][3];
            d0 = (fabsf(d0) < ERROR_OK) ? 0.0f : d0;
            d1 = (fabsf(d1) < ERROR_OK) ? 0.0f : d1;
            d2 = (fabsf(d2) < ERROR_OK) ? 0.0f : d2;
            d3 = (fabsf(d3) < ERROR_OK) ? 0.0f : d3;
            acc0 += d0 * d0;
            acc1 += d1 * d1;
            acc2 += d2 * d2;
            acc3 += d3 * d3;
        }
    }
    // per-block remainder iterations (not hit at N=2^25)
    for (; j < iters; ++j) {
        const int idx = base + j * BLOCK;
        v4f va = __builtin_nontemporal_load(&a[idx]);
        v4f vb = __builtin_nontemporal_load(&b[idx]);
        float d0 = va[0] - vb[0];
        float d1 = va[1] - vb[1];
        float d2 = va[2] - vb[2];
        float d3 = va[3] - vb[3];
        d0 = (fabsf(d0) < ERROR_OK) ? 0.0f : d0;
        d1 = (fabsf(d1) < ERROR_OK) ? 0.0f : d1;
        d2 = (fabsf(d2) < ERROR_OK) ? 0.0f : d2;
        d3 = (fabsf(d3) < ERROR_OK) ? 0.0f : d3;
        acc0 += d0 * d0;
        acc1 += d1 * d1;
        acc2 += d2 * d2;
        acc3 += d3 * d3;
    }
    // global leftover (n4 not divisible by GRID; not hit at N=2^25)
    for (int i = GRID * chunk + blockIdx.x * BLOCK + threadIdx.x;
         i < n4; i += GRID * BLOCK) {
        v4f va = __builtin_nontemporal_load(&a[i]);
        v4f vb = __builtin_nontemporal_load(&b[i]);
        float d0 = va[0] - vb[0];
        float d1 = va[1] - vb[1];
        float d2 = va[2] - vb[2];
        float d3 = va[3] - vb[3];
        d0 = (fabsf(d0) < ERROR_OK) ? 0.0f : d0;
        d1 = (fabsf(d1) < ERROR_OK) ? 0.0f : d1;
        d2 = (fabsf(d2) < ERROR_OK) ? 0.0f : d2;
        d3 = (fabsf(d3) < ERROR_OK) ? 0.0f : d3;
        acc0 += d0 * d0;
        acc1 += d1 * d1;
        acc2 += d2 * d2;
        acc3 += d3 * d3;
    }

    float sum = (acc0 + acc1) + (acc2 + acc3);

    // wave-64 butterfly reduce
    #pragma unroll
    for (int off = 32; off > 0; off >>= 1)
        sum += __shfl_down(sum, off, 64);

    __shared__ float smem[BLOCK / 64];
    const int lane = threadIdx.x & 63;
    const int wave = threadIdx.x >> 6;
    if (lane == 0) smem[wave] = sum;
    __syncthreads();

    if (threadIdx.x == 0) {
        float s = 0.0f;
        #pragma unroll
        for (int w = 0; w < BLOCK / 64; ++w) s += smem[w];
        partials[blockIdx.x] = s;
    }
}

// Stage 2: single block reduces GRID partials, scales by 1/N. Deterministic.
__global__ __launch_bounds__(BLOCK) void dz_final_kernel(
    const float* __restrict__ partials,
    float* __restrict__ out,
    int nparts,
    float inv_n)
{
    float sum = 0.0f;
    for (int i = threadIdx.x; i < nparts; i += BLOCK)
        sum += partials[i];

    #pragma unroll
    for (int off = 32; off > 0; off >>= 1)
        sum += __shfl_down(sum, off, 64);

    __shared__ float smem[BLOCK / 64];
    const int lane = threadIdx.x & 63;
    const int wave = threadIdx.x >> 6;
    if (lane == 0) smem[wave] = sum;
    __syncthreads();

    if (threadIdx.x == 0) {
        float s = 0.0f;
        #pragma unroll
        for (int w = 0; w < BLOCK / 64; ++w) s += smem[w];
        out[0] = s * inv_n;
    }
}

extern "C" void kernel_launch(void* const* d_in, const int* in_sizes, int n_in,
                              void* d_out, int out_size, void* d_ws, size_t ws_size,
                              hipStream_t stream) {
    const v4f* a    = (const v4f*)d_in[0];
    const v4f* b    = (const v4f*)d_in[1];
    float* out      = (float*)d_out;
    float* partials = (float*)d_ws;   // GRID floats = 8 KiB scratch

    const int n  = in_sizes[0];       // 33554432, divisible by 4
    const int n4 = n / 4;

    dz_partial_kernel<<<GRID, BLOCK, 0, stream>>>(a, b, partials, n4);
    dz_final_kernel<<<1, BLOCK, 0, stream>>>(partials, out, GRID, 1.0f / (float)n);
}